// Round 1
// baseline (129.522 us; speedup 1.0000x reference)
//
#include <hip/hip_runtime.h>
#include <math.h>

#define DV   256      // d_model
#define BB   64       // batch
#define LL   512      // seq len
#define DEG2 16       // 2 * n_degree
#define VV   8000     // vocab
#define CC   4        // n_category
#define LSPLIT 8      // L chunks per batch
#define LN_EPS 1e-5f

// ---------------- Kernel 1: per-row LayerNorm of the embedding table ----------------
__global__ void __launch_bounds__(256) ln_rows_kernel(
    const float* __restrict__ emb, const float* __restrict__ gamma,
    const float* __restrict__ beta, float* __restrict__ out)
{
    const int row  = blockIdx.x;
    const int d    = threadIdx.x;
    const int lane = d & 63;
    const int wv   = d >> 6;

    float v = emb[row * DV + d];

    __shared__ float s_part[4];
    __shared__ float s_bcast;

    // mean
    float s = v;
    #pragma unroll
    for (int off = 32; off > 0; off >>= 1) s += __shfl_xor(s, off);
    if (lane == 0) s_part[wv] = s;
    __syncthreads();
    if (d == 0) s_bcast = (s_part[0] + s_part[1] + s_part[2] + s_part[3]) * (1.0f / DV);
    __syncthreads();
    const float mu = s_bcast;

    // variance
    const float c = v - mu;
    float q = c * c;
    #pragma unroll
    for (int off = 32; off > 0; off >>= 1) q += __shfl_xor(q, off);
    if (lane == 0) s_part[wv] = q;
    __syncthreads();
    if (d == 0) s_bcast = rsqrtf((s_part[0] + s_part[1] + s_part[2] + s_part[3]) * (1.0f / DV) + LN_EPS);
    __syncthreads();
    const float rs = s_bcast;

    out[row * DV + d] = c * rs * gamma[d] + beta[d];
}

// ---------------- Kernel 2: gather + max-aggregate + eta blend + sum over L ----------------
__global__ void __launch_bounds__(256) gnn_kernel(
    const int*   __restrict__ x,
    const int*   __restrict__ nb_x,
    const int*   __restrict__ w_edge,
    const float* __restrict__ we_table,
    const float* __restrict__ eta_table,
    const float* __restrict__ norm_emb,
    float*       __restrict__ h_sum)
{
    const int b  = blockIdx.x;
    const int lc = blockIdx.y;
    const int d  = threadIdx.x;
    const int lN = LL / LSPLIT;
    const int l0 = lc * lN;

    __shared__ int   s_idx[DEG2 + 1];
    __shared__ float s_we[DEG2];
    __shared__ float s_eta;

    float acc = 0.0f;

    for (int l = l0; l < l0 + lN; ++l) {
        const int base = b * LL + l;
        if (d < DEG2) {
            s_idx[d] = nb_x[base * DEG2 + d];
            s_we[d]  = we_table[w_edge[base * DEG2 + d]];
        } else if (d == DEG2) {
            const int xv = x[base];
            s_idx[DEG2] = xv;
            s_eta = eta_table[xv];
        }
        __syncthreads();

        float m = -INFINITY;
        #pragma unroll
        for (int j = 0; j < DEG2; ++j) {
            m = fmaxf(m, s_we[j] * norm_emb[s_idx[j] * DV + d]);
        }
        const float selfv = norm_emb[s_idx[DEG2] * DV + d];
        const float eta   = s_eta;
        acc += (1.0f - eta) * m + eta * selfv;
        __syncthreads();
    }

    atomicAdd(&h_sum[b * DV + d], acc);
}

// ---------------- Kernel 3: final FC: scores = h_sum @ fc_w + fc_b ----------------
__global__ void __launch_bounds__(256) fc_kernel(
    const float* __restrict__ h_sum,
    const float* __restrict__ fc_w,
    const float* __restrict__ fc_b,
    float*       __restrict__ out)
{
    const int t = threadIdx.x;          // 256 = B*C
    const int b = t >> 2;
    const int c = t & 3;
    float s = 0.0f;
    #pragma unroll 8
    for (int dd = 0; dd < DV; ++dd) s += h_sum[b * DV + dd] * fc_w[dd * CC + c];
    out[b * CC + c] = s + fc_b[c];
}

extern "C" void kernel_launch(void* const* d_in, const int* in_sizes, int n_in,
                              void* d_out, int out_size, void* d_ws, size_t ws_size,
                              hipStream_t stream) {
    const int*   x        = (const int*)  d_in[0];
    const int*   nb_x     = (const int*)  d_in[1];
    const int*   w_edge   = (const int*)  d_in[2];
    const float* emb_w    = (const float*)d_in[3];
    const float* we_table = (const float*)d_in[4];
    const float* eta_tab  = (const float*)d_in[5];
    const float* ln_gamma = (const float*)d_in[6];
    const float* ln_beta  = (const float*)d_in[7];
    const float* fc_w     = (const float*)d_in[8];
    const float* fc_b     = (const float*)d_in[9];
    float* out = (float*)d_out;

    // workspace layout
    float* norm_emb = (float*)d_ws;                         // 8000*256*4 = 8,192,000 B
    float* h_sum    = (float*)((char*)d_ws + (size_t)VV * DV * sizeof(float)); // 64*256*4 = 65,536 B

    // zero the accumulator (poisoned workspace; re-run must be deterministic)
    hipMemsetAsync(h_sum, 0, (size_t)BB * DV * sizeof(float), stream);

    ln_rows_kernel<<<VV, DV, 0, stream>>>(emb_w, ln_gamma, ln_beta, norm_emb);

    dim3 grid2(BB, LSPLIT);
    gnn_kernel<<<grid2, DV, 0, stream>>>(x, nb_x, w_edge, we_table, eta_tab, norm_emb, h_sum);

    fc_kernel<<<1, DV, 0, stream>>>(h_sum, fc_w, fc_b, out);
}

// Round 2
// 48.232 us; speedup vs baseline: 2.6854x; 2.6854x over previous
//
#include <hip/hip_runtime.h>
#include <math.h>

#define DV   256      // d_model
#define BB   64       // batch
#define LL   512      // seq len
#define DEG2 16       // 2 * n_degree
#define VV   8000     // vocab
#define CC   4        // n_category
#define LSPLIT 64     // L chunks per batch (8 l per block, 2 per wave)
#define LN_EPS 1e-5f

typedef _Float16 half4 __attribute__((ext_vector_type(4)));
typedef float    f32x4 __attribute__((ext_vector_type(4)));

// ---------------- Kernel 1: LN the table once, emit fp16 rows ----------------
// one wave per row; lane covers 4 consecutive d
__global__ void __launch_bounds__(64) ln_rows_kernel(
    const float* __restrict__ emb, const float* __restrict__ gamma,
    const float* __restrict__ beta, half4* __restrict__ out)
{
    const int row = blockIdx.x;
    const int ln  = threadIdx.x;               // 0..63

    const f32x4 v = ((const f32x4*)(emb + row * DV))[ln];

    float s = v[0] + v[1] + v[2] + v[3];
    #pragma unroll
    for (int off = 32; off > 0; off >>= 1) s += __shfl_xor(s, off);
    const float mu = s * (1.0f / DV);

    f32x4 c;
    #pragma unroll
    for (int k = 0; k < 4; ++k) c[k] = v[k] - mu;

    float q = c[0]*c[0] + c[1]*c[1] + c[2]*c[2] + c[3]*c[3];
    #pragma unroll
    for (int off = 32; off > 0; off >>= 1) q += __shfl_xor(q, off);
    const float rs = rsqrtf(q * (1.0f / DV) + LN_EPS);

    const f32x4 g = ((const f32x4*)gamma)[ln];
    const f32x4 bt = ((const f32x4*)beta)[ln];

    half4 h;
    #pragma unroll
    for (int k = 0; k < 4; ++k) h[k] = (_Float16)(c[k] * rs * g[k] + bt[k]);
    out[row * 64 + ln] = h;
}

// ---------------- Kernel 2: massively-parallel random gathers ----------------
__global__ void __launch_bounds__(256) gather_kernel(
    const int* __restrict__ w_edge, const float* __restrict__ we_table,
    const int* __restrict__ x,      const float* __restrict__ eta_table,
    float* __restrict__ we_flat,    float* __restrict__ eta_flat)
{
    const int i = blockIdx.x * 256 + threadIdx.x;   // 0 .. BB*LL*DEG2-1
    we_flat[i] = we_table[w_edge[i]];
    if (i < BB * LL) eta_flat[i] = eta_table[x[i]];
}

// ---------------- Kernel 3: gather + max-aggregate + blend + partial L-sum ----------------
// block = (b, lc); 4 waves; each wave handles 2 l's, covering all 256 d (4/lane)
__global__ void __launch_bounds__(256) gnn_kernel(
    const int*   __restrict__ nb_x,
    const int*   __restrict__ x,
    const float* __restrict__ we_flat,
    const float* __restrict__ eta_flat,
    const half4* __restrict__ norm_emb,   // [VV*64]
    float*       __restrict__ h_part)     // [BB][LSPLIT][DV]
{
    const int b   = blockIdx.x;
    const int lc  = blockIdx.y;
    const int w   = __builtin_amdgcn_readfirstlane(threadIdx.x >> 6); // SGPR wave id
    const int ln  = threadIdx.x & 63;

    f32x4 acc = {0.0f, 0.0f, 0.0f, 0.0f};

    #pragma unroll
    for (int li = 0; li < 2; ++li) {
        const int l    = lc * 8 + w * 2 + li;     // wave-uniform
        const int base = b * LL + l;              // wave-uniform -> scalar loads

        const int*   nb  = nb_x    + base * DEG2;
        const float* wep = we_flat + base * DEG2;

        f32x4 m = {-INFINITY, -INFINITY, -INFINITY, -INFINITY};
        #pragma unroll
        for (int j = 0; j < DEG2; ++j) {
            const int   idx = nb[j];              // SGPR
            const float wej = wep[j];             // SGPR
            const half4 e = norm_emb[idx * 64 + ln];
            #pragma unroll
            for (int k = 0; k < 4; ++k)
                m[k] = fmaxf(m[k], wej * (float)e[k]);
        }

        const int   sidx = x[base];               // SGPR
        const float eta  = eta_flat[base];        // SGPR
        const half4 se   = norm_emb[sidx * 64 + ln];
        #pragma unroll
        for (int k = 0; k < 4; ++k)
            acc[k] += (1.0f - eta) * m[k] + eta * (float)se[k];
    }

    // reduce the 4 waves' partials in LDS, wave 0 writes
    __shared__ float s_acc[4][DV];
    ((f32x4*)s_acc[w])[ln] = acc;
    __syncthreads();
    if (w == 0) {
        f32x4 r0 = ((f32x4*)s_acc[0])[ln];
        f32x4 r1 = ((f32x4*)s_acc[1])[ln];
        f32x4 r2 = ((f32x4*)s_acc[2])[ln];
        f32x4 r3 = ((f32x4*)s_acc[3])[ln];
        f32x4 r;
        #pragma unroll
        for (int k = 0; k < 4; ++k) r[k] = r0[k] + r1[k] + r2[k] + r3[k];
        ((f32x4*)(h_part + (b * LSPLIT + lc) * DV))[ln] = r;
    }
}

// ---------------- Kernel 4: reduce partials over lc, then FC ----------------
__global__ void __launch_bounds__(256) fc_kernel(
    const float* __restrict__ h_part,
    const float* __restrict__ fc_w,
    const float* __restrict__ fc_b,
    float*       __restrict__ out)
{
    const int b  = blockIdx.x;
    const int d  = threadIdx.x;       // 0..255
    const int w  = d >> 6;
    const int ln = d & 63;

    float h = 0.0f;
    #pragma unroll 8
    for (int lc = 0; lc < LSPLIT; ++lc)
        h += h_part[(b * LSPLIT + lc) * DV + d];

    float p[CC];
    #pragma unroll
    for (int c = 0; c < CC; ++c) p[c] = h * fc_w[d * CC + c];

    #pragma unroll
    for (int c = 0; c < CC; ++c)
        #pragma unroll
        for (int off = 32; off > 0; off >>= 1) p[c] += __shfl_xor(p[c], off);

    __shared__ float s_red[4][CC];
    if (ln == 0) {
        #pragma unroll
        for (int c = 0; c < CC; ++c) s_red[w][c] = p[c];
    }
    __syncthreads();
    if (d < CC)
        out[b * CC + d] = s_red[0][d] + s_red[1][d] + s_red[2][d] + s_red[3][d] + fc_b[d];
}

extern "C" void kernel_launch(void* const* d_in, const int* in_sizes, int n_in,
                              void* d_out, int out_size, void* d_ws, size_t ws_size,
                              hipStream_t stream) {
    const int*   x        = (const int*)  d_in[0];
    const int*   nb_x     = (const int*)  d_in[1];
    const int*   w_edge   = (const int*)  d_in[2];
    const float* emb_w    = (const float*)d_in[3];
    const float* we_table = (const float*)d_in[4];
    const float* eta_tab  = (const float*)d_in[5];
    const float* ln_gamma = (const float*)d_in[6];
    const float* ln_beta  = (const float*)d_in[7];
    const float* fc_w     = (const float*)d_in[8];
    const float* fc_b     = (const float*)d_in[9];
    float* out = (float*)d_out;

    // workspace layout (all 256B-aligned)
    char* ws = (char*)d_ws;
    half4* norm_emb = (half4*)(ws);                            // 8000*256*2  = 4,096,000 B
    float* we_flat  = (float*)(ws + 4096000);                  // 524288*4    = 2,097,152 B
    float* eta_flat = (float*)(ws + 4096000 + 2097152);        // 32768*4     =   131,072 B
    float* h_part   = (float*)(ws + 4096000 + 2097152 + 131072); // 64*64*256*4 = 4,194,304 B

    ln_rows_kernel<<<VV, 64, 0, stream>>>(emb_w, ln_gamma, ln_beta, norm_emb);

    gather_kernel<<<(BB * LL * DEG2) / 256, 256, 0, stream>>>(
        w_edge, we_table, x, eta_tab, we_flat, eta_flat);

    dim3 grid3(BB, LSPLIT);
    gnn_kernel<<<grid3, 256, 0, stream>>>(nb_x, x, we_flat, eta_flat, norm_emb, h_part);

    fc_kernel<<<BB, 256, 0, stream>>>(h_part, fc_w, fc_b, out);
}

// Round 3
// 44.555 us; speedup vs baseline: 2.9070x; 1.0825x over previous
//
#include <hip/hip_runtime.h>
#include <math.h>

#define DV   256      // d_model
#define BB   64       // batch
#define LL   512      // seq len
#define DEG2 16       // 2 * n_degree
#define VV   8000     // vocab
#define CC   4        // n_category
#define LPW  4        // l's per wave
#define NW   4        // waves per block
#define LCB  (LPW*NW) // l's per block = 16
#define NLC  (LL/LCB) // 32 blocks along L
#define LN_EPS 1e-5f

typedef _Float16 half4 __attribute__((ext_vector_type(4)));
typedef float    f32x4 __attribute__((ext_vector_type(4)));

// ---------------- Kernel 1: LN the table once, emit fp16 rows ----------------
__global__ void __launch_bounds__(64) ln_rows_kernel(
    const float* __restrict__ emb, const float* __restrict__ gamma,
    const float* __restrict__ beta, half4* __restrict__ out)
{
    const int row = blockIdx.x;
    const int ln  = threadIdx.x;               // 0..63

    const f32x4 v = ((const f32x4*)(emb + row * DV))[ln];

    float s = v[0] + v[1] + v[2] + v[3];
    #pragma unroll
    for (int off = 32; off > 0; off >>= 1) s += __shfl_xor(s, off);
    const float mu = s * (1.0f / DV);

    f32x4 c;
    #pragma unroll
    for (int k = 0; k < 4; ++k) c[k] = v[k] - mu;

    float q = c[0]*c[0] + c[1]*c[1] + c[2]*c[2] + c[3]*c[3];
    #pragma unroll
    for (int off = 32; off > 0; off >>= 1) q += __shfl_xor(q, off);
    const float rs = rsqrtf(q * (1.0f / DV) + LN_EPS);

    const f32x4 g  = ((const f32x4*)gamma)[ln];
    const f32x4 bt = ((const f32x4*)beta)[ln];

    half4 h;
    #pragma unroll
    for (int k = 0; k < 4; ++k) h[k] = (_Float16)(c[k] * rs * g[k] + bt[k]);
    out[row * 64 + ln] = h;
}

// ---------------- Kernel 2: fused edge-gather + max-aggregate + blend + partial L-sum ----------------
// block = (b, lc); 4 waves; each wave owns 4 consecutive l's (= 64 edges, one per lane)
__global__ void __launch_bounds__(256) gnn_kernel(
    const int*   __restrict__ nb_x,
    const int*   __restrict__ w_edge,
    const float* __restrict__ we_table,
    const int*   __restrict__ x,
    const float* __restrict__ eta_table,
    const half4* __restrict__ norm_emb,   // [VV*64]
    float*       __restrict__ h_part)     // [BB][NLC][DV]
{
    const int b   = blockIdx.x;
    const int lc  = blockIdx.y;
    const int tid = threadIdx.x;
    const int w   = tid >> 6;
    const int ln  = tid & 63;

    const int l0   = lc * LCB + w * LPW;        // wave's first l
    const int base = b * LL + l0;               // wave-uniform

    // ---- phase 1: coalesced edge loads + random we gather (one edge per lane) ----
    const int   nbv = nb_x  [base * DEG2 + ln];
    const int   eiv = w_edge[base * DEG2 + ln];
    const float wev = we_table[eiv];            // random 4B gather from 256MB table

    int   xv = 0; float etv = 0.0f;
    if (ln < LPW) { xv = x[base + ln]; etv = eta_table[xv]; }

    __shared__ int2  s_pair[NW][64];            // {nb_idx, we_bits}
    __shared__ int   s_self[NW][LPW];
    __shared__ float s_eta [NW][LPW];

    int2 pr; pr.x = nbv; pr.y = __float_as_int(wev);
    s_pair[w][ln] = pr;
    if (ln < LPW) { s_self[w][ln] = xv; s_eta[w][ln] = etv; }
    __syncthreads();

    // ---- phase 2: row gathers from L2-resident fp16 table ----
    f32x4 acc = {0.0f, 0.0f, 0.0f, 0.0f};

    #pragma unroll
    for (int li = 0; li < LPW; ++li) {
        f32x4 m = {-INFINITY, -INFINITY, -INFINITY, -INFINITY};
        #pragma unroll
        for (int j = 0; j < DEG2; ++j) {
            const int2  p   = s_pair[w][li * DEG2 + j];  // uniform addr -> LDS broadcast
            const int   idx = p.x;
            const float wej = __int_as_float(p.y);
            const half4 e   = norm_emb[idx * 64 + ln];
            #pragma unroll
            for (int k = 0; k < 4; ++k)
                m[k] = fmaxf(m[k], wej * (float)e[k]);
        }
        const int   sidx = s_self[w][li];
        const float eta  = s_eta [w][li];
        const half4 se   = norm_emb[sidx * 64 + ln];
        #pragma unroll
        for (int k = 0; k < 4; ++k)
            acc[k] += (1.0f - eta) * m[k] + eta * (float)se[k];
    }

    // ---- phase 3: reduce the 4 waves' partials, one write per block ----
    __shared__ float s_acc[NW][DV];
    ((f32x4*)s_acc[w])[ln] = acc;
    __syncthreads();
    if (w == 0) {
        f32x4 r0 = ((f32x4*)s_acc[0])[ln];
        f32x4 r1 = ((f32x4*)s_acc[1])[ln];
        f32x4 r2 = ((f32x4*)s_acc[2])[ln];
        f32x4 r3 = ((f32x4*)s_acc[3])[ln];
        f32x4 r;
        #pragma unroll
        for (int k = 0; k < 4; ++k) r[k] = r0[k] + r1[k] + r2[k] + r3[k];
        ((f32x4*)(h_part + (b * NLC + lc) * DV))[ln] = r;
    }
}

// ---------------- Kernel 3: reduce partials over lc, then FC ----------------
__global__ void __launch_bounds__(256) fc_kernel(
    const float* __restrict__ h_part,
    const float* __restrict__ fc_w,
    const float* __restrict__ fc_b,
    float*       __restrict__ out)
{
    const int b  = blockIdx.x;
    const int d  = threadIdx.x;       // 0..255
    const int w  = d >> 6;
    const int ln = d & 63;

    float h = 0.0f;
    #pragma unroll 8
    for (int lc = 0; lc < NLC; ++lc)
        h += h_part[(b * NLC + lc) * DV + d];

    float p[CC];
    #pragma unroll
    for (int c = 0; c < CC; ++c) p[c] = h * fc_w[d * CC + c];

    #pragma unroll
    for (int c = 0; c < CC; ++c)
        #pragma unroll
        for (int off = 32; off > 0; off >>= 1) p[c] += __shfl_xor(p[c], off);

    __shared__ float s_red[4][CC];
    if (ln == 0) {
        #pragma unroll
        for (int c = 0; c < CC; ++c) s_red[w][c] = p[c];
    }
    __syncthreads();
    if (d < CC)
        out[b * CC + d] = s_red[0][d] + s_red[1][d] + s_red[2][d] + s_red[3][d] + fc_b[d];
}

extern "C" void kernel_launch(void* const* d_in, const int* in_sizes, int n_in,
                              void* d_out, int out_size, void* d_ws, size_t ws_size,
                              hipStream_t stream) {
    const int*   x        = (const int*)  d_in[0];
    const int*   nb_x     = (const int*)  d_in[1];
    const int*   w_edge   = (const int*)  d_in[2];
    const float* emb_w    = (const float*)d_in[3];
    const float* we_table = (const float*)d_in[4];
    const float* eta_tab  = (const float*)d_in[5];
    const float* ln_gamma = (const float*)d_in[6];
    const float* ln_beta  = (const float*)d_in[7];
    const float* fc_w     = (const float*)d_in[8];
    const float* fc_b     = (const float*)d_in[9];
    float* out = (float*)d_out;

    // workspace layout
    char* ws = (char*)d_ws;
    half4* norm_emb = (half4*)(ws);                 // 8000*256*2 = 4,096,000 B
    float* h_part   = (float*)(ws + 4096000);       // 64*32*256*4 = 2,097,152 B

    ln_rows_kernel<<<VV, 64, 0, stream>>>(emb_w, ln_gamma, ln_beta, norm_emb);

    dim3 grid2(BB, NLC);
    gnn_kernel<<<grid2, 256, 0, stream>>>(nb_x, w_edge, we_table, x, eta_tab,
                                          norm_emb, h_part);

    fc_kernel<<<BB, 256, 0, stream>>>(h_part, fc_w, fc_b, out);
}